// Round 10
// baseline (186.339 us; speedup 1.0000x reference)
//
#include <hip/hip_runtime.h>
#include <hip/hip_bf16.h>

// GNNRefiner: out = xyz + max_k( relu([x_i, x_j-x_i]·W1 + b1)·W2 + b2 )
// Factorization: e·W1 = x_i·(A-B) + x_j·B  with A=W1[0:387], B=W1[387:774].
// Pipeline: zero_hist -> prep(fused,+hist) -> scan -> assign(perm/rank, approx x-sort)
//           -> knn (exact fp32, rank-translated output) -> bf16 MFMA GEMM (sorted rows)
//           -> final (XCD-slab swizzle, persistent wave, dbuf global_load_lds staging).
// Sorting gives each XCD an L2-resident V window (random gather was 30MB of LLC misses).

#define N 8192
#define NTILES 32   // N/256
#define TD 384      // TOKEN_DIM
#define KNN 16
#define DX 387      // TD + 3
#define KP 416      // DX padded to multiple of 32
#define NF 768      // 2*TD output cols of fused GEMM
#define INFF __builtin_inff()

typedef __attribute__((ext_vector_type(8))) short short8;
typedef __attribute__((ext_vector_type(4))) float f32x4;
typedef __attribute__((ext_vector_type(2))) float f32x2;

// ---------------- packed fp32 helpers (bit-identical to scalar ops, 2 cands/instr) ----------------

__device__ __forceinline__ f32x2 pk_mul(f32x2 a, f32x2 b) {
    f32x2 r; asm("v_pk_mul_f32 %0, %1, %2" : "=v"(r) : "v"(a), "v"(b)); return r;
}
__device__ __forceinline__ f32x2 pk_add(f32x2 a, f32x2 b) {
    f32x2 r; asm("v_pk_add_f32 %0, %1, %2" : "=v"(r) : "v"(a), "v"(b)); return r;
}
__device__ __forceinline__ f32x2 pk_sub(f32x2 a, f32x2 b) {  // a - b, same rounding as fsub
    f32x2 r; asm("v_pk_add_f32 %0, %1, %2 neg_lo:[0,1] neg_hi:[0,1]" : "=v"(r) : "v"(a), "v"(b)); return r;
}
__device__ __forceinline__ f32x2 pk_fma(f32x2 a, f32x2 b, f32x2 c) {
    f32x2 r; asm("v_pk_fma_f32 %0, %1, %2, %3" : "=v"(r) : "v"(a), "v"(b), "v"(c)); return r;
}

// d2 = (qw + sq_j) - 2*dot, dot = fma(qz,z, fma(qy,y, mul(qx,x)))  [bit-identical to ref]
__device__ __forceinline__ void dist4(f32x2 qx, f32x2 qy, f32x2 qz, f32x2 qw,
                                      f32x2 x01, f32x2 x23, f32x2 y01, f32x2 y23,
                                      f32x2 z01, f32x2 z23, f32x2 s01, f32x2 s23,
                                      f32x2& d01, f32x2& d23) {
    f32x2 dot01 = pk_fma(qz, z01, pk_fma(qy, y01, pk_mul(qx, x01)));
    f32x2 dot23 = pk_fma(qz, z23, pk_fma(qy, y23, pk_mul(qx, x23)));
    d01 = pk_sub(pk_add(qw, s01), pk_add(dot01, dot01));  // dot+dot == 2*dot exactly
    d23 = pk_sub(pk_add(qw, s23), pk_add(dot23, dot23));
}

// bin for the approximate x-sort (identical expression everywhere -> deterministic)
__device__ __forceinline__ int xbin(float x) {
    int b = (int)((x + 4.0f) * 32.0f);
    return b < 0 ? 0 : (b > 255 ? 255 : b);
}

// ---------------- sort-prep kernels ----------------

__global__ void zero_hist(int* __restrict__ hist) { hist[threadIdx.x] = 0; }

__global__ void scan_kernel(const int* __restrict__ hist, int* __restrict__ cut) {
    __shared__ int tmp[256];
    int t = threadIdx.x;
    int v = hist[t];
    tmp[t] = v;
    __syncthreads();
    for (int off = 1; off < 256; off <<= 1) {
        int add = (t >= off) ? tmp[t - off] : 0;
        __syncthreads();
        tmp[t] += add;
        __syncthreads();
    }
    cut[t] = tmp[t] - v;   // exclusive prefix
}

__global__ void assign_kernel(const float* __restrict__ xyz, int* __restrict__ cut,
                              int* __restrict__ perm, int* __restrict__ rank) {
    int i = blockIdx.x * 256 + threadIdx.x;
    int bin = xbin(xyz[i*3]);
    int pos = atomicAdd(&cut[bin], 1);
    perm[pos] = i;
    rank[i] = pos;
}

// ---------------- fused prep: Xb rows + point tiles + Wpt + x-histogram ----------------

__global__ void prep_all(const float* __restrict__ feat, const float* __restrict__ xyz,
                         const float* __restrict__ W1,
                         float* __restrict__ tiles, __hip_bfloat16* __restrict__ Xb,
                         __hip_bfloat16* __restrict__ Wpt, int* __restrict__ hist) {
    int b = blockIdx.x;
    int t = threadIdx.x;
    if (b < N) {
        if (t < 96) {  // vectorized feat copy: 96 x float4 -> 4 x bf16
            float4 f = reinterpret_cast<const float4*>(feat + (size_t)b*TD)[t];
            __hip_bfloat16 h[4] = {__float2bfloat16(f.x), __float2bfloat16(f.y),
                                   __float2bfloat16(f.z), __float2bfloat16(f.w)};
            *reinterpret_cast<ulonglong1*>(Xb + b*KP + t*4) = *reinterpret_cast<ulonglong1*>(h);
        } else if (t == 96) {  // xyz tail + zero pad
            for (int d = TD; d < KP; ++d) {
                float v = (d < DX) ? xyz[b*3 + (d - TD)] : 0.f;
                Xb[b*KP + d] = __float2bfloat16(v);
            }
        } else if (t == 97) {  // point tile entry + histogram
            float x = xyz[b*3+0], y = xyz[b*3+1], z = xyz[b*3+2];
            float sq = __fadd_rn(__fadd_rn(__fmul_rn(x,x), __fmul_rn(y,y)), __fmul_rn(z,z));
            float* tp = tiles + (b >> 8) * 1024 + (b & 255);
            tp[0] = x; tp[256] = y; tp[512] = z; tp[768] = sq;
            atomicAdd(&hist[xbin(x)], 1);
        }
    } else {
        int f = b - N;  // 0..767
        for (int k = t; k < KP; k += 256) {
            float v = 0.f;
            if (k < DX) {
                if (f < TD) v = W1[k*TD + f] - W1[(DX+k)*TD + f];
                else        v = W1[(DX+k)*TD + (f - TD)];
            }
            Wpt[f*KP + k] = __float2bfloat16(v);
        }
    }
}

// ---------------- knn helpers ----------------

__device__ __forceinline__ float dpp_shr1_f(float v) {
    return __uint_as_float((unsigned)__builtin_amdgcn_update_dpp(
        (int)__float_as_uint(v), (int)__float_as_uint(v), 0x111, 0xF, 0xF, false));
}
__device__ __forceinline__ int dpp_shr1_i(int v) {
    return __builtin_amdgcn_update_dpp(v, v, 0x111, 0xF, 0xF, false);
}
__device__ __forceinline__ float rdlane_f(float v, int src) {
    return __uint_as_float(__builtin_amdgcn_readlane(__float_as_uint(v), src));
}

// Sorted-by-lane top-16 insert: list element s in lane s (s=0..15), ascending (d2, idx).
__device__ __forceinline__ void insert16(float dv, int jbase, float Tq,
                                         float& ld, int& li, float& Tl, int lane) {
    unsigned long long m = __ballot((dv <= Tq) && (dv < Tl));
    while (m) {
        int src = (int)__ffsll(m) - 1;
        float cd = rdlane_f(dv, src);
        int   cj = jbase + src*4;
        bool lt = (ld < cd) || (ld == cd && li < cj);
        int pos = (int)__popcll(__ballot(lt) & 0xFFFFull);
        float ud = dpp_shr1_f(ld);
        int   ui = dpp_shr1_i(li);
        ld = (lane == pos) ? cd : ((lane > pos) ? ud : ld);
        li = (lane == pos) ? cj : ((lane > pos) ? ui : li);
        Tl = rdlane_f(ld, 15);
        m &= ~(1ull << src);
        m &= __ballot(dv < Tl);
    }
}

// ---------------- knn: wave-PAIR per 4 queries, each wave scans 16 tiles ----------------
// Output entries are RANK-translated (sorted positions); selection stays by (d, orig idx).

__global__ void __launch_bounds__(256) knn_kernel(const float* __restrict__ tiles,
                                                  const int* __restrict__ rank,
                                                  int* __restrict__ knn) {
    __shared__ float sdl[2][2][4][16];
    __shared__ int   sjl[2][2][4][16];
    const int lane = threadIdx.x & 63;
    const int wv   = threadIdx.x >> 6;
    const int g    = wv >> 1;                    // query group in block (0,1)
    const int p    = wv & 1;                     // half index (0,1)
    const int i0   = (blockIdx.x * 2 + g) * 4;   // 4 consecutive queries
    const int st   = i0 >> 8;
    const int sl   = (i0 & 255) >> 2;            // self lane; query q -> slot q
    const int t0   = p * 16;                     // this wave's first tile

    const float* qp = tiles + st * 1024 + (i0 & 255);
    float4 QX = *(const float4*)(qp);
    float4 QY = *(const float4*)(qp + 256);
    float4 QZ = *(const float4*)(qp + 512);
    float4 QW = *(const float4*)(qp + 768);
    f32x2 qx2[4], qy2[4], qz2[4], qw2[4];
    {
        float qxa[4] = {QX.x,QX.y,QX.z,QX.w}, qya[4] = {QY.x,QY.y,QY.z,QY.w};
        float qza[4] = {QZ.x,QZ.y,QZ.z,QZ.w}, qwa[4] = {QW.x,QW.y,QW.z,QW.w};
        #pragma unroll
        for (int q = 0; q < 4; ++q) {
            qx2[q] = (f32x2){qxa[q], qxa[q]};
            qy2[q] = (f32x2){qya[q], qya[q]};
            qz2[q] = (f32x2){qza[q], qza[q]};
            qw2[q] = (f32x2){qwa[q], qwa[q]};
        }
    }

    const float* lbase = tiles + lane*4;
    const bool is_self_lane = (lane == sl);

    // ---- pass 1: per-lane minima over this wave's 16 tiles (reg prefetch, wraps) ----
    float mn[4] = {INFF, INFF, INFF, INFF};
    {
        const float* bp = lbase + t0*1024;
        float4 X = *(const float4*)(bp);
        float4 Y = *(const float4*)(bp + 256);
        float4 Z = *(const float4*)(bp + 512);
        float4 S = *(const float4*)(bp + 768);
        for (int tt = 0; tt < 16; ++tt) {
            const int t = t0 + tt;
            const float* np = lbase + (t0 + ((tt+1) & 15)) * 1024;
            float4 Xn = *(const float4*)(np);
            float4 Yn = *(const float4*)(np + 256);
            float4 Zn = *(const float4*)(np + 512);
            float4 Sn = *(const float4*)(np + 768);

            f32x2 x01 = {X.x,X.y}, x23 = {X.z,X.w};
            f32x2 y01 = {Y.x,Y.y}, y23 = {Y.z,Y.w};
            f32x2 z01 = {Z.x,Z.y}, z23 = {Z.z,Z.w};
            f32x2 s01 = {S.x,S.y}, s23 = {S.z,S.w};
            const bool selft = (t == st) && is_self_lane;
            #pragma unroll
            for (int q = 0; q < 4; ++q) {
                f32x2 d01, d23;
                dist4(qx2[q], qy2[q], qz2[q], qw2[q],
                      x01, x23, y01, y23, z01, z23, s01, s23, d01, d23);
                if (selft) {
                    if      (q == 0) d01[0] = INFF;
                    else if (q == 1) d01[1] = INFF;
                    else if (q == 2) d23[0] = INFF;
                    else             d23[1] = INFF;
                }
                mn[q] = fminf(mn[q], fminf(fminf(d01[0], d01[1]), fminf(d23[0], d23[1])));
            }
            X = Xn; Y = Yn; Z = Zn; S = Sn;
        }
    }

    // ---- T[q] = exact 16th smallest of 64 lane minima, radix-select (no LDS ops) ----
    unsigned ub[4];
    unsigned long long alive[4];
    int need[4];
    #pragma unroll
    for (int q = 0; q < 4; ++q) {
        unsigned x = __float_as_uint(mn[q]);
        ub[q] = ((int)x < 0) ? ~x : (x | 0x80000000u);
        alive[q] = ~0ull;
        need[q] = KNN;
    }
    for (int b = 31; b >= 0; --b) {
        #pragma unroll
        for (int q = 0; q < 4; ++q) {
            unsigned long long ones  = __ballot(((ub[q] >> b) & 1u) != 0u);
            unsigned long long zeros = alive[q] & ~ones;
            int cz = (int)__popcll(zeros);
            bool tz = (cz >= need[q]);
            alive[q] = tz ? zeros : (alive[q] & ones);
            need[q]  = tz ? need[q] : (need[q] - cz);
        }
    }
    float T[4];
    #pragma unroll
    for (int q = 0; q < 4; ++q)
        T[q] = rdlane_f(mn[q], (int)__ffsll(alive[q]) - 1);

    // ---- pass 2: exact top-16 of this half over prefiltered candidates ----
    float ld[4] = {INFF, INFF, INFF, INFF};
    int   li[4] = {-1, -1, -1, -1};
    float Tl[4] = {INFF, INFF, INFF, INFF};
    {
        const float* bp = lbase + t0*1024;
        float4 X = *(const float4*)(bp);
        float4 Y = *(const float4*)(bp + 256);
        float4 Z = *(const float4*)(bp + 512);
        float4 S = *(const float4*)(bp + 768);
        for (int tt = 0; tt < 16; ++tt) {
            const int t = t0 + tt;
            const float* np = lbase + (t0 + ((tt+1) & 15)) * 1024;
            float4 Xn = *(const float4*)(np);
            float4 Yn = *(const float4*)(np + 256);
            float4 Zn = *(const float4*)(np + 512);
            float4 Sn = *(const float4*)(np + 768);

            f32x2 x01 = {X.x,X.y}, x23 = {X.z,X.w};
            f32x2 y01 = {Y.x,Y.y}, y23 = {Y.z,Y.w};
            f32x2 z01 = {Z.x,Z.y}, z23 = {Z.z,Z.w};
            f32x2 s01 = {S.x,S.y}, s23 = {S.z,S.w};
            const bool selft = (t == st) && is_self_lane;
            #pragma unroll
            for (int q = 0; q < 4; ++q) {
                f32x2 d01, d23;
                dist4(qx2[q], qy2[q], qz2[q], qw2[q],
                      x01, x23, y01, y23, z01, z23, s01, s23, d01, d23);
                if (selft) {
                    if      (q == 0) d01[0] = INFF;
                    else if (q == 1) d01[1] = INFF;
                    else if (q == 2) d23[0] = INFF;
                    else             d23[1] = INFF;
                }
                float tmin = fminf(fminf(d01[0], d01[1]), fminf(d23[0], d23[1]));
                if (__ballot(tmin <= T[q])) {
                    insert16(d01[0], t*256 + 0, T[q], ld[q], li[q], Tl[q], lane);
                    insert16(d01[1], t*256 + 1, T[q], ld[q], li[q], Tl[q], lane);
                    insert16(d23[0], t*256 + 2, T[q], ld[q], li[q], Tl[q], lane);
                    insert16(d23[1], t*256 + 3, T[q], ld[q], li[q], Tl[q], lane);
                }
            }
            X = Xn; Y = Yn; Z = Zn; S = Sn;
        }
    }

    // ---- merge the two halves' sorted-16 lists (bitonic half-cleaner), rank-translate ----
    if (lane < KNN) {
        #pragma unroll
        for (int q = 0; q < 4; ++q) { sdl[g][p][q][lane] = ld[q]; sjl[g][p][q][lane] = li[q]; }
    }
    __syncthreads();
    if (p == 0 && lane < KNN) {
        #pragma unroll
        for (int q = 0; q < 4; ++q) {
            float ad = sdl[g][0][q][lane];      int aj = sjl[g][0][q][lane];
            float bd = sdl[g][1][q][15 - lane]; int bj = sjl[g][1][q][15 - lane];
            bool alt = (ad < bd) || (ad == bd && aj < bj);
            knn[(i0 + q)*KNN + lane] = rank[alt ? aj : bj];
        }
    }
}

// ---------------- GEMM: Ub/Vb[sorted s][384] = Xb[perm[s]] @ Wpt^T (+ b1 on U) ----------------
// 1 wave per block, 64 rows x 64 cols; C/D: col = lane&15, row = (lane>>4)*4 + q
// A-loads were already 16-row scattered, so perm indirection is ~free; writes stay linear.

__global__ void __launch_bounds__(64) gemm_kernel(const __hip_bfloat16* __restrict__ Xb,
                                                  const __hip_bfloat16* __restrict__ Wpt,
                                                  const float* __restrict__ b1,
                                                  const int* __restrict__ perm,
                                                  __hip_bfloat16* __restrict__ Ub,
                                                  __hip_bfloat16* __restrict__ Vb) {
    const int lane = threadIdx.x;
    const int i0   = blockIdx.x * 64;
    const int f0   = blockIdx.y * 64;
    const int lm   = lane & 15;
    const int lk   = (lane >> 4) * 8;

    f32x4 acc[4][4];
    #pragma unroll
    for (int r = 0; r < 4; ++r)
        #pragma unroll
        for (int c = 0; c < 4; ++c)
            acc[r][c] = (f32x4){0.f, 0.f, 0.f, 0.f};

    const __hip_bfloat16* xb[4];
    #pragma unroll
    for (int r = 0; r < 4; ++r)
        xb[r] = Xb + (size_t)perm[i0 + r*16 + lm] * KP + lk;
    const __hip_bfloat16* wbase = Wpt + (size_t)(f0 + lm) * KP + lk;

    #pragma unroll
    for (int kk = 0; kk < 13; ++kk) {
        short8 a[4], b[4];
        #pragma unroll
        for (int r = 0; r < 4; ++r)
            a[r] = *reinterpret_cast<const short8*>(xb[r] + kk*32);
        #pragma unroll
        for (int c = 0; c < 4; ++c)
            b[c] = *reinterpret_cast<const short8*>(wbase + (size_t)c*16*KP + kk*32);
        #pragma unroll
        for (int r = 0; r < 4; ++r)
            #pragma unroll
            for (int c = 0; c < 4; ++c)
                acc[r][c] = __builtin_amdgcn_mfma_f32_16x16x32_bf16(a[r], b[c], acc[r][c], 0, 0, 0);
    }

    const bool isU = (f0 < TD);
    __hip_bfloat16* outb = isU ? (Ub + f0) : (Vb + (f0 - TD));
    float bias[4] = {0.f, 0.f, 0.f, 0.f};
    if (isU) {
        #pragma unroll
        for (int c = 0; c < 4; ++c) bias[c] = b1[f0 + c*16 + lm];
    }
    const int crow = (lane >> 4) * 4;
    #pragma unroll
    for (int r = 0; r < 4; ++r)
        #pragma unroll
        for (int c = 0; c < 4; ++c)
            #pragma unroll
            for (int q = 0; q < 4; ++q)
                outb[(size_t)(i0 + r*16 + crow + q) * TD + c*16 + lm] =
                    __float2bfloat16(acc[r][c][q] + bias[c]);
}

// ---------------- final: XCD-slab swizzle, persistent wave, dbuf async staging ----------------
// Block b -> XCD (b&7) slab: s0 = (b&7)*1024 + (b>>3)*16 + wv*8 (bijective, 512 blocks).
// Each XCD gathers V rows from its ~1-2MB sorted window -> L2-resident.

__device__ __forceinline__ float bflo(unsigned w) { return __uint_as_float(w << 16); }
__device__ __forceinline__ float bfhi(unsigned w) { return __uint_as_float(w & 0xFFFF0000u); }

template<int CTRL>
__device__ __forceinline__ float dppf(float v) {
    return __uint_as_float((unsigned)__builtin_amdgcn_update_dpp(
        0, (int)__float_as_uint(v), CTRL, 0xF, 0xF, true));
}

__device__ __forceinline__ void stage16(const void* g, void* l) {
    __builtin_amdgcn_global_load_lds(
        (const __attribute__((address_space(1))) void*)g,
        (__attribute__((address_space(3))) void*)l, 16, 0, 0);
}

#define BUFB 13312   // 12288 V (16 rows x 768B, source-swizzled) + 1024 U

__global__ void __launch_bounds__(128) final_kernel(const __hip_bfloat16* __restrict__ Ub,
                                                    const __hip_bfloat16* __restrict__ Vb,
                                                    const int* __restrict__ knn,
                                                    const int* __restrict__ perm,
                                                    const float* __restrict__ xyz,
                                                    const float* __restrict__ W2,
                                                    const float* __restrict__ b2,
                                                    float* __restrict__ out) {
    __shared__ __align__(16) char lds_all[2 * 2 * BUFB];
    const int lane = threadIdx.x & 63;
    const int wv   = threadIdx.x >> 6;
    char* my = lds_all + wv * (2 * BUFB);
    const int s0  = (blockIdx.x & 7) * (N/8) + (blockIdx.x >> 3) * 16 + wv * 8;
    const int l16 = lane & 15;
    const int k   = lane >> 2;       // neighbor slot 0..15
    const int qt  = lane & 3;        // dim quarter 0..3 (96 dims each)
    const float4* Wq = reinterpret_cast<const float4*>(W2 + (size_t)qt*96*3);

    // stage sorted point s: V rows (rank-indexed gather, source pre-swizzled) + U row
    auto stage = [&](char* buf, int jreg, int s) {
        #pragma unroll
        for (int t = 0; t < 12; ++t) {
            int C  = t*64 + lane;
            int kk = C / 48;
            int wp = C - kk*48;
            int w  = wp ^ (kk & 7);
            int jk = __shfl(jreg, kk);
            stage16((const char*)Vb + (size_t)jk*768 + w*16, buf + t*1024);
        }
        int w = (lane < 48) ? lane : 0;
        stage16((const char*)Ub + (size_t)s*768 + w*16, buf + 12288);
    };

    // compute one point from its LDS buffer (validated round-8 math + reductions)
    auto compute = [&](const char* buf, float& r0, float& r1, float& r2) {
        float s0_ = 0.f, s1_ = 0.f, s2_ = 0.f;
        #pragma unroll
        for (int cc = 0; cc < 12; ++cc) {
            uint4 vv = *reinterpret_cast<const uint4*>(buf + ((k*48 + ((qt*12+cc) ^ (k&7))) << 4));
            uint4 uu = *reinterpret_cast<const uint4*>(buf + ((768 + qt*12 + cc) << 4));
            float w[24];
            #pragma unroll
            for (int p = 0; p < 6; ++p) {
                float4 wp = Wq[cc*6 + p];
                w[p*4+0] = wp.x; w[p*4+1] = wp.y; w[p*4+2] = wp.z; w[p*4+3] = wp.w;
            }
            unsigned va[4] = {vv.x, vv.y, vv.z, vv.w};
            unsigned ua[4] = {uu.x, uu.y, uu.z, uu.w};
            #pragma unroll
            for (int m = 0; m < 4; ++m) {
                float hlo = fmaxf(bflo(ua[m]) + bflo(va[m]), 0.f);
                float hhi = fmaxf(bfhi(ua[m]) + bfhi(va[m]), 0.f);
                const int d3 = (2*m)*3;
                s0_ = fmaf(hlo, w[d3+0], s0_);
                s1_ = fmaf(hlo, w[d3+1], s1_);
                s2_ = fmaf(hlo, w[d3+2], s2_);
                s0_ = fmaf(hhi, w[d3+3], s0_);
                s1_ = fmaf(hhi, w[d3+4], s1_);
                s2_ = fmaf(hhi, w[d3+5], s2_);
            }
        }
        s0_ += dppf<0xB1>(s0_); s0_ += dppf<0x4E>(s0_);
        s1_ += dppf<0xB1>(s1_); s1_ += dppf<0x4E>(s1_);
        s2_ += dppf<0xB1>(s2_); s2_ += dppf<0x4E>(s2_);
        s0_ = fmaxf(s0_, dppf<0x124>(s0_)); s0_ = fmaxf(s0_, dppf<0x128>(s0_));
        s1_ = fmaxf(s1_, dppf<0x124>(s1_)); s1_ = fmaxf(s1_, dppf<0x128>(s1_));
        s2_ = fmaxf(s2_, dppf<0x124>(s2_)); s2_ = fmaxf(s2_, dppf<0x128>(s2_));
        s0_ = fmaxf(s0_, __shfl_xor(s0_, 16)); s0_ = fmaxf(s0_, __shfl_xor(s0_, 32));
        s1_ = fmaxf(s1_, __shfl_xor(s1_, 16)); s1_ = fmaxf(s1_, __shfl_xor(s1_, 32));
        s2_ = fmaxf(s2_, __shfl_xor(s2_, 16)); s2_ = fmaxf(s2_, __shfl_xor(s2_, 32));
        r0 = s0_; r1 = s1_; r2 = s2_;
    };

    int oarr[8];
    // ---- prologue: stage point s0, prefetch knn(s0+1) ----
    oarr[0] = perm[s0 + 0];
    int j_a = knn[oarr[0]*KNN + l16];
    stage(my, j_a, s0 + 0);
    oarr[1] = perm[s0 + 1];
    int j_b = knn[oarr[1]*KNN + l16];
    asm volatile("s_waitcnt vmcnt(0)" ::: "memory");
    __builtin_amdgcn_sched_barrier(0);

    float ox[8], oy[8], oz[8];
    #pragma unroll
    for (int p = 0; p < 8; ++p) {           // full unroll -> all indexing static
        char* cur = my + (p & 1) * BUFB;
        char* nxt = my + ((p + 1) & 1) * BUFB;
        if (p < 7) {
            int jn = (p & 1) ? j_a : j_b;   // j for point p+1
            stage(nxt, jn, s0 + p + 1);
        }
        if (p < 6) {                        // prefetch perm+knn for point p+2
            int o2 = perm[s0 + p + 2];
            oarr[p + 2] = o2;
            int jl = knn[o2*KNN + l16];
            if (p & 1) j_b = jl; else j_a = jl;
        }
        compute(cur, ox[p], oy[p], oz[p]);
        asm volatile("s_waitcnt vmcnt(0)" ::: "memory");   // stage(p+1) + prefetch done
        __builtin_amdgcn_sched_barrier(0);
    }

    if (lane == 0) {
        float bb0 = b2[0], bb1 = b2[1], bb2 = b2[2];
        #pragma unroll
        for (int p = 0; p < 8; ++p) {
            int o = oarr[p];
            out[o*3 + 0] = xyz[o*3 + 0] + ox[p] + bb0;
            out[o*3 + 1] = xyz[o*3 + 1] + oy[p] + bb1;
            out[o*3 + 2] = xyz[o*3 + 2] + oz[p] + bb2;
        }
    }
}

// ---------------- launch ----------------

extern "C" void kernel_launch(void* const* d_in, const int* in_sizes, int n_in,
                              void* d_out, int out_size, void* d_ws, size_t ws_size,
                              hipStream_t stream) {
    const float* xyz  = (const float*)d_in[0];
    const float* feat = (const float*)d_in[1];
    const float* W1   = (const float*)d_in[2];
    const float* b1   = (const float*)d_in[3];
    const float* W2   = (const float*)d_in[4];
    const float* b2   = (const float*)d_in[5];
    float* out = (float*)d_out;

    char* ws = (char*)d_ws;
    int*            knn   = (int*)(ws + 0);                   //   524288 B
    float*          tiles = (float*)(ws + 524288);            //   131072 B
    __hip_bfloat16* Xb    = (__hip_bfloat16*)(ws + 655360);   //  6815744 B
    __hip_bfloat16* Wpt   = (__hip_bfloat16*)(ws + 7471104);  //   638976 B
    __hip_bfloat16* Ub    = (__hip_bfloat16*)(ws + 8110080);  //  6291456 B
    __hip_bfloat16* Vb    = (__hip_bfloat16*)(ws + 14401536); //  6291456 B
    int*            perm  = (int*)(ws + 20692992);            //    32768 B
    int*            rank  = (int*)(ws + 20725760);            //    32768 B
    int*            hist  = (int*)(ws + 20758528);            //     1024 B
    int*            cut   = (int*)(ws + 20759552);            //     1024 B -> end 20760576

    zero_hist    <<<dim3(1),           dim3(256), 0, stream>>>(hist);
    prep_all     <<<dim3(N + NF),      dim3(256), 0, stream>>>(feat, xyz, W1, tiles, Xb, Wpt, hist);
    scan_kernel  <<<dim3(1),           dim3(256), 0, stream>>>(hist, cut);
    assign_kernel<<<dim3(N/256),       dim3(256), 0, stream>>>(xyz, cut, perm, rank);
    knn_kernel   <<<dim3(N/8),         dim3(256), 0, stream>>>(tiles, rank, knn);
    gemm_kernel  <<<dim3(N/64, NF/64), dim3(64),  0, stream>>>(Xb, Wpt, b1, perm, Ub, Vb);
    final_kernel <<<dim3(N/16),        dim3(128), 0, stream>>>(Ub, Vb, knn, perm, xyz, W2, b2, out);
}

// Round 11
// 98.374 us; speedup vs baseline: 1.8942x; 1.8942x over previous
//
#include <hip/hip_runtime.h>
#include <hip/hip_bf16.h>

// GNNRefiner: out = xyz + max_k( relu([x_i, x_j-x_i]·W1 + b1)·W2 + b2 )
// Factorization: e·W1 = x_i·(A-B) + x_j·B  with A=W1[0:387], B=W1[387:774].
// Pipeline: prep(fused) -> knn (two-pass exact fp32, wave-pair tile split, radix-T)
//           -> bf16 MFMA GEMM (+b1, split Ub/Vb) -> final (dim-parallel coalesced row
//           reads, depth-2 load pipeline, buffered partials + pipelined DPP reduce).
// Round-10 lesson: k-parallel 16B/lane gathers (64 lines/instr) were the 72-81us wall;
// dim-parallel row reads are ~12 lines/instr with scalar row base.

#define N 8192
#define NTILES 32   // N/256
#define TD 384      // TOKEN_DIM
#define KNN 16
#define DX 387      // TD + 3
#define KP 416      // DX padded to multiple of 32
#define NF 768      // 2*TD output cols of fused GEMM
#define INFF __builtin_inff()

typedef __attribute__((ext_vector_type(8))) short short8;
typedef __attribute__((ext_vector_type(4))) float f32x4;
typedef __attribute__((ext_vector_type(2))) float f32x2;

// ---------------- packed fp32 helpers (bit-identical to scalar ops, 2 cands/instr) ----------------

__device__ __forceinline__ f32x2 pk_mul(f32x2 a, f32x2 b) {
    f32x2 r; asm("v_pk_mul_f32 %0, %1, %2" : "=v"(r) : "v"(a), "v"(b)); return r;
}
__device__ __forceinline__ f32x2 pk_add(f32x2 a, f32x2 b) {
    f32x2 r; asm("v_pk_add_f32 %0, %1, %2" : "=v"(r) : "v"(a), "v"(b)); return r;
}
__device__ __forceinline__ f32x2 pk_sub(f32x2 a, f32x2 b) {  // a - b, same rounding as fsub
    f32x2 r; asm("v_pk_add_f32 %0, %1, %2 neg_lo:[0,1] neg_hi:[0,1]" : "=v"(r) : "v"(a), "v"(b)); return r;
}
__device__ __forceinline__ f32x2 pk_fma(f32x2 a, f32x2 b, f32x2 c) {
    f32x2 r; asm("v_pk_fma_f32 %0, %1, %2, %3" : "=v"(r) : "v"(a), "v"(b), "v"(c)); return r;
}

// d2 = (qw + sq_j) - 2*dot, dot = fma(qz,z, fma(qy,y, mul(qx,x)))  [bit-identical to ref]
__device__ __forceinline__ void dist4(f32x2 qx, f32x2 qy, f32x2 qz, f32x2 qw,
                                      f32x2 x01, f32x2 x23, f32x2 y01, f32x2 y23,
                                      f32x2 z01, f32x2 z23, f32x2 s01, f32x2 s23,
                                      f32x2& d01, f32x2& d23) {
    f32x2 dot01 = pk_fma(qz, z01, pk_fma(qy, y01, pk_mul(qx, x01)));
    f32x2 dot23 = pk_fma(qz, z23, pk_fma(qy, y23, pk_mul(qx, x23)));
    d01 = pk_sub(pk_add(qw, s01), pk_add(dot01, dot01));  // dot+dot == 2*dot exactly
    d23 = pk_sub(pk_add(qw, s23), pk_add(dot23, dot23));
}

// ---------------- fused prep: Xb rows + point tiles + Wpt ----------------

__global__ void prep_all(const float* __restrict__ feat, const float* __restrict__ xyz,
                         const float* __restrict__ W1,
                         float* __restrict__ tiles, __hip_bfloat16* __restrict__ Xb,
                         __hip_bfloat16* __restrict__ Wpt) {
    int b = blockIdx.x;
    int t = threadIdx.x;
    if (b < N) {
        if (t < 96) {  // vectorized feat copy: 96 x float4 -> 4 x bf16
            float4 f = reinterpret_cast<const float4*>(feat + (size_t)b*TD)[t];
            __hip_bfloat16 h[4] = {__float2bfloat16(f.x), __float2bfloat16(f.y),
                                   __float2bfloat16(f.z), __float2bfloat16(f.w)};
            *reinterpret_cast<ulonglong1*>(Xb + b*KP + t*4) = *reinterpret_cast<ulonglong1*>(h);
        } else if (t == 96) {  // xyz tail + zero pad
            for (int d = TD; d < KP; ++d) {
                float v = (d < DX) ? xyz[b*3 + (d - TD)] : 0.f;
                Xb[b*KP + d] = __float2bfloat16(v);
            }
        } else if (t == 97) {  // point tile entry
            float x = xyz[b*3+0], y = xyz[b*3+1], z = xyz[b*3+2];
            float sq = __fadd_rn(__fadd_rn(__fmul_rn(x,x), __fmul_rn(y,y)), __fmul_rn(z,z));
            float* tp = tiles + (b >> 8) * 1024 + (b & 255);
            tp[0] = x; tp[256] = y; tp[512] = z; tp[768] = sq;
        }
    } else {
        int f = b - N;  // 0..767
        for (int k = t; k < KP; k += 256) {
            float v = 0.f;
            if (k < DX) {
                if (f < TD) v = W1[k*TD + f] - W1[(DX+k)*TD + f];
                else        v = W1[(DX+k)*TD + (f - TD)];
            }
            Wpt[f*KP + k] = __float2bfloat16(v);
        }
    }
}

// ---------------- knn helpers ----------------

__device__ __forceinline__ float dpp_shr1_f(float v) {
    return __uint_as_float((unsigned)__builtin_amdgcn_update_dpp(
        (int)__float_as_uint(v), (int)__float_as_uint(v), 0x111, 0xF, 0xF, false));
}
__device__ __forceinline__ int dpp_shr1_i(int v) {
    return __builtin_amdgcn_update_dpp(v, v, 0x111, 0xF, 0xF, false);
}
__device__ __forceinline__ float rdlane_f(float v, int src) {
    return __uint_as_float(__builtin_amdgcn_readlane(__float_as_uint(v), src));
}

// Sorted-by-lane top-16 insert: list element s in lane s (s=0..15), ascending (d2, idx).
__device__ __forceinline__ void insert16(float dv, int jbase, float Tq,
                                         float& ld, int& li, float& Tl, int lane) {
    unsigned long long m = __ballot((dv <= Tq) && (dv < Tl));
    while (m) {
        int src = (int)__ffsll(m) - 1;
        float cd = rdlane_f(dv, src);
        int   cj = jbase + src*4;
        bool lt = (ld < cd) || (ld == cd && li < cj);
        int pos = (int)__popcll(__ballot(lt) & 0xFFFFull);
        float ud = dpp_shr1_f(ld);
        int   ui = dpp_shr1_i(li);
        ld = (lane == pos) ? cd : ((lane > pos) ? ud : ld);
        li = (lane == pos) ? cj : ((lane > pos) ? ui : li);
        Tl = rdlane_f(ld, 15);
        m &= ~(1ull << src);
        m &= __ballot(dv < Tl);
    }
}

// ---------------- knn: wave-PAIR per 4 queries, each wave scans 16 tiles ----------------

__global__ void __launch_bounds__(256) knn_kernel(const float* __restrict__ tiles,
                                                  int* __restrict__ knn) {
    __shared__ float sdl[2][2][4][16];
    __shared__ int   sjl[2][2][4][16];
    const int lane = threadIdx.x & 63;
    const int wv   = threadIdx.x >> 6;
    const int g    = wv >> 1;                    // query group in block (0,1)
    const int p    = wv & 1;                     // half index (0,1)
    const int i0   = (blockIdx.x * 2 + g) * 4;   // 4 consecutive queries
    const int st   = i0 >> 8;
    const int sl   = (i0 & 255) >> 2;            // self lane; query q -> slot q
    const int t0   = p * 16;                     // this wave's first tile

    const float* qp = tiles + st * 1024 + (i0 & 255);
    float4 QX = *(const float4*)(qp);
    float4 QY = *(const float4*)(qp + 256);
    float4 QZ = *(const float4*)(qp + 512);
    float4 QW = *(const float4*)(qp + 768);
    f32x2 qx2[4], qy2[4], qz2[4], qw2[4];
    {
        float qxa[4] = {QX.x,QX.y,QX.z,QX.w}, qya[4] = {QY.x,QY.y,QY.z,QY.w};
        float qza[4] = {QZ.x,QZ.y,QZ.z,QZ.w}, qwa[4] = {QW.x,QW.y,QW.z,QW.w};
        #pragma unroll
        for (int q = 0; q < 4; ++q) {
            qx2[q] = (f32x2){qxa[q], qxa[q]};
            qy2[q] = (f32x2){qya[q], qya[q]};
            qz2[q] = (f32x2){qza[q], qza[q]};
            qw2[q] = (f32x2){qwa[q], qwa[q]};
        }
    }

    const float* lbase = tiles + lane*4;
    const bool is_self_lane = (lane == sl);

    // ---- pass 1: per-lane minima over this wave's 16 tiles (reg prefetch, wraps) ----
    float mn[4] = {INFF, INFF, INFF, INFF};
    {
        const float* bp = lbase + t0*1024;
        float4 X = *(const float4*)(bp);
        float4 Y = *(const float4*)(bp + 256);
        float4 Z = *(const float4*)(bp + 512);
        float4 S = *(const float4*)(bp + 768);
        for (int tt = 0; tt < 16; ++tt) {
            const int t = t0 + tt;
            const float* np = lbase + (t0 + ((tt+1) & 15)) * 1024;
            float4 Xn = *(const float4*)(np);
            float4 Yn = *(const float4*)(np + 256);
            float4 Zn = *(const float4*)(np + 512);
            float4 Sn = *(const float4*)(np + 768);

            f32x2 x01 = {X.x,X.y}, x23 = {X.z,X.w};
            f32x2 y01 = {Y.x,Y.y}, y23 = {Y.z,Y.w};
            f32x2 z01 = {Z.x,Z.y}, z23 = {Z.z,Z.w};
            f32x2 s01 = {S.x,S.y}, s23 = {S.z,S.w};
            const bool selft = (t == st) && is_self_lane;
            #pragma unroll
            for (int q = 0; q < 4; ++q) {
                f32x2 d01, d23;
                dist4(qx2[q], qy2[q], qz2[q], qw2[q],
                      x01, x23, y01, y23, z01, z23, s01, s23, d01, d23);
                if (selft) {
                    if      (q == 0) d01[0] = INFF;
                    else if (q == 1) d01[1] = INFF;
                    else if (q == 2) d23[0] = INFF;
                    else             d23[1] = INFF;
                }
                mn[q] = fminf(mn[q], fminf(fminf(d01[0], d01[1]), fminf(d23[0], d23[1])));
            }
            X = Xn; Y = Yn; Z = Zn; S = Sn;
        }
    }

    // ---- T[q] = exact 16th smallest of 64 lane minima, radix-select (no LDS ops) ----
    unsigned ub[4];
    unsigned long long alive[4];
    int need[4];
    #pragma unroll
    for (int q = 0; q < 4; ++q) {
        unsigned x = __float_as_uint(mn[q]);
        ub[q] = ((int)x < 0) ? ~x : (x | 0x80000000u);
        alive[q] = ~0ull;
        need[q] = KNN;
    }
    for (int b = 31; b >= 0; --b) {
        #pragma unroll
        for (int q = 0; q < 4; ++q) {
            unsigned long long ones  = __ballot(((ub[q] >> b) & 1u) != 0u);
            unsigned long long zeros = alive[q] & ~ones;
            int cz = (int)__popcll(zeros);
            bool tz = (cz >= need[q]);
            alive[q] = tz ? zeros : (alive[q] & ones);
            need[q]  = tz ? need[q] : (need[q] - cz);
        }
    }
    float T[4];
    #pragma unroll
    for (int q = 0; q < 4; ++q)
        T[q] = rdlane_f(mn[q], (int)__ffsll(alive[q]) - 1);

    // ---- pass 2: exact top-16 of this half over prefiltered candidates ----
    float ld[4] = {INFF, INFF, INFF, INFF};
    int   li[4] = {-1, -1, -1, -1};
    float Tl[4] = {INFF, INFF, INFF, INFF};
    {
        const float* bp = lbase + t0*1024;
        float4 X = *(const float4*)(bp);
        float4 Y = *(const float4*)(bp + 256);
        float4 Z = *(const float4*)(bp + 512);
        float4 S = *(const float4*)(bp + 768);
        for (int tt = 0; tt < 16; ++tt) {
            const int t = t0 + tt;
            const float* np = lbase + (t0 + ((tt+1) & 15)) * 1024;
            float4 Xn = *(const float4*)(np);
            float4 Yn = *(const float4*)(np + 256);
            float4 Zn = *(const float4*)(np + 512);
            float4 Sn = *(const float4*)(np + 768);

            f32x2 x01 = {X.x,X.y}, x23 = {X.z,X.w};
            f32x2 y01 = {Y.x,Y.y}, y23 = {Y.z,Y.w};
            f32x2 z01 = {Z.x,Z.y}, z23 = {Z.z,Z.w};
            f32x2 s01 = {S.x,S.y}, s23 = {S.z,S.w};
            const bool selft = (t == st) && is_self_lane;
            #pragma unroll
            for (int q = 0; q < 4; ++q) {
                f32x2 d01, d23;
                dist4(qx2[q], qy2[q], qz2[q], qw2[q],
                      x01, x23, y01, y23, z01, z23, s01, s23, d01, d23);
                if (selft) {
                    if      (q == 0) d01[0] = INFF;
                    else if (q == 1) d01[1] = INFF;
                    else if (q == 2) d23[0] = INFF;
                    else             d23[1] = INFF;
                }
                float tmin = fminf(fminf(d01[0], d01[1]), fminf(d23[0], d23[1]));
                if (__ballot(tmin <= T[q])) {
                    insert16(d01[0], t*256 + 0, T[q], ld[q], li[q], Tl[q], lane);
                    insert16(d01[1], t*256 + 1, T[q], ld[q], li[q], Tl[q], lane);
                    insert16(d23[0], t*256 + 2, T[q], ld[q], li[q], Tl[q], lane);
                    insert16(d23[1], t*256 + 3, T[q], ld[q], li[q], Tl[q], lane);
                }
            }
            X = Xn; Y = Yn; Z = Zn; S = Sn;
        }
    }

    // ---- merge the two halves' sorted-16 lists (bitonic half-cleaner) ----
    if (lane < KNN) {
        #pragma unroll
        for (int q = 0; q < 4; ++q) { sdl[g][p][q][lane] = ld[q]; sjl[g][p][q][lane] = li[q]; }
    }
    __syncthreads();
    if (p == 0 && lane < KNN) {
        #pragma unroll
        for (int q = 0; q < 4; ++q) {
            float ad = sdl[g][0][q][lane];      int aj = sjl[g][0][q][lane];
            float bd = sdl[g][1][q][15 - lane]; int bj = sjl[g][1][q][15 - lane];
            bool alt = (ad < bd) || (ad == bd && aj < bj);
            knn[(i0 + q)*KNN + lane] = alt ? aj : bj;
        }
    }
}

// ---------------- GEMM: Ub/Vb[N][384] = Xb @ Wpt^T (+ b1 on U), bf16 out ----------------
// 1 wave per block, 64 rows x 64 cols; C/D: col = lane&15, row = (lane>>4)*4 + q

__global__ void __launch_bounds__(64) gemm_kernel(const __hip_bfloat16* __restrict__ Xb,
                                                  const __hip_bfloat16* __restrict__ Wpt,
                                                  const float* __restrict__ b1,
                                                  __hip_bfloat16* __restrict__ Ub,
                                                  __hip_bfloat16* __restrict__ Vb) {
    const int lane = threadIdx.x;
    const int i0   = blockIdx.x * 64;
    const int f0   = blockIdx.y * 64;
    const int lm   = lane & 15;
    const int lk   = (lane >> 4) * 8;

    f32x4 acc[4][4];
    #pragma unroll
    for (int r = 0; r < 4; ++r)
        #pragma unroll
        for (int c = 0; c < 4; ++c)
            acc[r][c] = (f32x4){0.f, 0.f, 0.f, 0.f};

    const __hip_bfloat16* xbase = Xb  + (size_t)(i0 + lm) * KP + lk;
    const __hip_bfloat16* wbase = Wpt + (size_t)(f0 + lm) * KP + lk;

    #pragma unroll
    for (int kk = 0; kk < 13; ++kk) {
        short8 a[4], b[4];
        #pragma unroll
        for (int r = 0; r < 4; ++r)
            a[r] = *reinterpret_cast<const short8*>(xbase + (size_t)r*16*KP + kk*32);
        #pragma unroll
        for (int c = 0; c < 4; ++c)
            b[c] = *reinterpret_cast<const short8*>(wbase + (size_t)c*16*KP + kk*32);
        #pragma unroll
        for (int r = 0; r < 4; ++r)
            #pragma unroll
            for (int c = 0; c < 4; ++c)
                acc[r][c] = __builtin_amdgcn_mfma_f32_16x16x32_bf16(a[r], b[c], acc[r][c], 0, 0, 0);
    }

    const bool isU = (f0 < TD);
    __hip_bfloat16* outb = isU ? (Ub + f0) : (Vb + (f0 - TD));
    float bias[4] = {0.f, 0.f, 0.f, 0.f};
    if (isU) {
        #pragma unroll
        for (int c = 0; c < 4; ++c) bias[c] = b1[f0 + c*16 + lm];
    }
    const int crow = (lane >> 4) * 4;
    #pragma unroll
    for (int r = 0; r < 4; ++r)
        #pragma unroll
        for (int c = 0; c < 4; ++c)
            #pragma unroll
            for (int q = 0; q < 4; ++q)
                outb[(size_t)(i0 + r*16 + crow + q) * TD + c*16 + lm] =
                    __float2bfloat16(acc[r][c][q] + bias[c]);
}

// ---------------- final: dim-parallel (lane owns 6 dims), coalesced row reads ----------------
// One wave per point. Per k: whole wave reads V row j_k (3 coalesced dword loads,
// SGPR row base via readlane). Depth-2 batch pipeline (4 k per batch, 12 regs in
// flight). Partials buffered per k; reduction at end: rotate-allreduce within 16-lane
// rows (DPP, VALU pipe) + 2 independent shfl_xor stages -> fully pipelined.

__device__ __forceinline__ float bflo(unsigned w) { return __uint_as_float(w << 16); }
__device__ __forceinline__ float bfhi(unsigned w) { return __uint_as_float(w & 0xFFFF0000u); }

template<int CTRL>
__device__ __forceinline__ float dppf(float v) {
    return __uint_as_float((unsigned)__builtin_amdgcn_update_dpp(
        0, (int)__float_as_uint(v), CTRL, 0xF, 0xF, true));
}

__global__ void __launch_bounds__(256) final_kernel(const __hip_bfloat16* __restrict__ Ub,
                                                    const __hip_bfloat16* __restrict__ Vb,
                                                    const int* __restrict__ knn,
                                                    const float* __restrict__ xyz,
                                                    const float* __restrict__ W2,
                                                    const float* __restrict__ b2,
                                                    float* __restrict__ out) {
    const int lane = threadIdx.x & 63;
    const int wv   = threadIdx.x >> 6;
    const int i    = blockIdx.x * 4 + wv;
    const int d0   = lane * 6;

    int jreg = knn[i*KNN + (lane & 15)];

    // U row (b1 already folded by gemm) + W2 slice for this lane's 6 dims
    float u[6], w2l[6][3];
    {
        const unsigned* rowU = reinterpret_cast<const unsigned*>(Ub + (size_t)i * TD) + lane*3;
        unsigned a0 = rowU[0], a1 = rowU[1], a2 = rowU[2];
        u[0] = bflo(a0); u[1] = bfhi(a0);
        u[2] = bflo(a1); u[3] = bfhi(a1);
        u[4] = bflo(a2); u[5] = bfhi(a2);
    }
    #pragma unroll
    for (int t = 0; t < 6; ++t)
        #pragma unroll
        for (int c = 0; c < 3; ++c) w2l[t][c] = W2[(d0 + t)*3 + c];

    const unsigned* vbase = reinterpret_cast<const unsigned*>(Vb);
    const int voff = lane * 3;

    float pk0[16], pk1[16], pk2[16];
    unsigned va[2][4][3];

    // prologue: issue batch 0 (k=0..3)
    #pragma unroll
    for (int t = 0; t < 4; ++t) {
        int j = __builtin_amdgcn_readlane(jreg, t);
        const unsigned* rv = vbase + (size_t)j * 192 + voff;
        va[0][t][0] = rv[0]; va[0][t][1] = rv[1]; va[0][t][2] = rv[2];
    }
    __builtin_amdgcn_sched_barrier(0);

    #pragma unroll
    for (int b = 0; b < 4; ++b) {
        if (b < 3) {   // issue next batch (pipelined ahead of this batch's compute)
            #pragma unroll
            for (int t = 0; t < 4; ++t) {
                int j = __builtin_amdgcn_readlane(jreg, (b+1)*4 + t);
                const unsigned* rv = vbase + (size_t)j * 192 + voff;
                va[(b+1)&1][t][0] = rv[0];
                va[(b+1)&1][t][1] = rv[1];
                va[(b+1)&1][t][2] = rv[2];
            }
            __builtin_amdgcn_sched_barrier(0);
        }
        #pragma unroll
        for (int t = 0; t < 4; ++t) {
            const int kk = b*4 + t;
            unsigned a0 = va[b&1][t][0], a1 = va[b&1][t][1], a2 = va[b&1][t][2];
            float v0 = bflo(a0), v1 = bfhi(a0);
            float v2 = bflo(a1), v3 = bfhi(a1);
            float v4 = bflo(a2), v5 = bfhi(a2);
            float h0 = fmaxf(u[0] + v0, 0.f), h1 = fmaxf(u[1] + v1, 0.f);
            float h2 = fmaxf(u[2] + v2, 0.f), h3 = fmaxf(u[3] + v3, 0.f);
            float h4 = fmaxf(u[4] + v4, 0.f), h5 = fmaxf(u[5] + v5, 0.f);
            float s0 = 0.f, s1 = 0.f, s2 = 0.f;
            s0 = fmaf(h0, w2l[0][0], s0); s1 = fmaf(h0, w2l[0][1], s1); s2 = fmaf(h0, w2l[0][2], s2);
            s0 = fmaf(h1, w2l[1][0], s0); s1 = fmaf(h1, w2l[1][1], s1); s2 = fmaf(h1, w2l[1][2], s2);
            s0 = fmaf(h2, w2l[2][0], s0); s1 = fmaf(h2, w2l[2][1], s1); s2 = fmaf(h2, w2l[2][2], s2);
            s0 = fmaf(h3, w2l[3][0], s0); s1 = fmaf(h3, w2l[3][1], s1); s2 = fmaf(h3, w2l[3][2], s2);
            s0 = fmaf(h4, w2l[4][0], s0); s1 = fmaf(h4, w2l[4][1], s1); s2 = fmaf(h4, w2l[4][2], s2);
            s0 = fmaf(h5, w2l[5][0], s0); s1 = fmaf(h5, w2l[5][1], s1); s2 = fmaf(h5, w2l[5][2], s2);
            pk0[kk] = s0; pk1[kk] = s1; pk2[kk] = s2;
        }
    }

    // ---- pipelined reductions: rotate-allreduce within 16-lane rows (DPP), then
    //      cross-row via shfl_xor(16,32). 48 independent chains -> pipelined. ----
    #pragma unroll
    for (int kk = 0; kk < 16; ++kk) {
        float r0 = pk0[kk], r1 = pk1[kk], r2 = pk2[kk];
        r0 += dppf<0x121>(r0); r1 += dppf<0x121>(r1); r2 += dppf<0x121>(r2);
        r0 += dppf<0x122>(r0); r1 += dppf<0x122>(r1); r2 += dppf<0x122>(r2);
        r0 += dppf<0x124>(r0); r1 += dppf<0x124>(r1); r2 += dppf<0x124>(r2);
        r0 += dppf<0x128>(r0); r1 += dppf<0x128>(r1); r2 += dppf<0x128>(r2);
        r0 += __shfl_xor(r0, 16); r1 += __shfl_xor(r1, 16); r2 += __shfl_xor(r2, 16);
        r0 += __shfl_xor(r0, 32); r1 += __shfl_xor(r1, 32); r2 += __shfl_xor(r2, 32);
        pk0[kk] = r0; pk1[kk] = r1; pk2[kk] = r2;
    }
    float mx0 = pk0[0], mx1 = pk1[0], mx2 = pk2[0];
    #pragma unroll
    for (int kk = 1; kk < 16; ++kk) {
        mx0 = fmaxf(mx0, pk0[kk]);
        mx1 = fmaxf(mx1, pk1[kk]);
        mx2 = fmaxf(mx2, pk2[kk]);
    }

    if (lane == 0) {
        out[i*3+0] = xyz[i*3+0] + mx0 + b2[0];
        out[i*3+1] = xyz[i*3+1] + mx1 + b2[1];
        out[i*3+2] = xyz[i*3+2] + mx2 + b2[2];
    }
}

// ---------------- launch ----------------

extern "C" void kernel_launch(void* const* d_in, const int* in_sizes, int n_in,
                              void* d_out, int out_size, void* d_ws, size_t ws_size,
                              hipStream_t stream) {
    const float* xyz  = (const float*)d_in[0];
    const float* feat = (const float*)d_in[1];
    const float* W1   = (const float*)d_in[2];
    const float* b1   = (const float*)d_in[3];
    const float* W2   = (const float*)d_in[4];
    const float* b2   = (const float*)d_in[5];
    float* out = (float*)d_out;

    char* ws = (char*)d_ws;
    int*            knn   = (int*)(ws + 0);                   //   524288 B
    float*          tiles = (float*)(ws + 524288);            //   131072 B
    __hip_bfloat16* Xb    = (__hip_bfloat16*)(ws + 655360);   //  6815744 B
    __hip_bfloat16* Wpt   = (__hip_bfloat16*)(ws + 7471104);  //   638976 B
    __hip_bfloat16* Ub    = (__hip_bfloat16*)(ws + 8110080);  //  6291456 B
    __hip_bfloat16* Vb    = (__hip_bfloat16*)(ws + 14401536); //  6291456 B -> end 20692992

    prep_all   <<<dim3(N + NF),      dim3(256), 0, stream>>>(feat, xyz, W1, tiles, Xb, Wpt);
    knn_kernel <<<dim3(N/8),         dim3(256), 0, stream>>>(tiles, knn);
    gemm_kernel<<<dim3(N/64, NF/64), dim3(64),  0, stream>>>(Xb, Wpt, b1, Ub, Vb);
    final_kernel<<<dim3(N/4),        dim3(256), 0, stream>>>(Ub, Vb, knn, xyz, W2, b2, out);
}